// Round 3
// baseline (359.295 us; speedup 1.0000x reference)
//
#include <hip/hip_runtime.h>

// Problem constants
#define B_ 2048
#define S_ 512
#define I_ 256
#define F_ 256
#define NG 8   // number of partial-groups for the W2 fold

typedef float v4f __attribute__((ext_vector_type(4)));

// Workspace layout (in floats)
#define OFF_W    1024                    // w[B,F]   (hidden @ W1^T)
#define OFF_SW   (OFF_W + B_*F_)         // Sw[B]    (row sums of w)
#define OFF_U    (OFF_SW + B_)           // u[B,S]
#define OFF_P    (OFF_U + B_*S_)         // p[B,S]
#define OFF_RP   (OFF_P + B_*S_)         // rp[NG][512] partial r = Wfc@W2
// total floats = OFF_RP + NG*512 = 2,628,608 (~10.5 MB)

// ---------------------------------------------------------------------------
// k_pre: blocks 0..511  : w[b,f] = hidden[b,:].W1[f,:], Sw[b] (4 batches/block)
//        blocks 512..519: partial fold rp[g][j] = sum_{i in g's 32} Wfc[i]*W2[i,j]
__global__ __launch_bounds__(256) void k_pre(
    const float* __restrict__ hidden, const float* __restrict__ W1,
    const float* __restrict__ W2, const float* __restrict__ Wfc,
    float* __restrict__ ws) {
  const int tid = threadIdx.x;

  if (blockIdx.x >= B_ / 4) {
    // ---- W2 fold partials: 8 blocks, 32 i's each (deterministic, no atomics)
    const int g = blockIdx.x - B_ / 4;
    float acc0 = 0.f, acc1 = 0.f;
#pragma unroll 8
    for (int ii = 0; ii < 32; ++ii) {
      const int i = g * 32 + ii;
      const float f = Wfc[i];
      acc0 += f * W2[(size_t)i * (I_ + F_) + tid];
      acc1 += f * W2[(size_t)i * (I_ + F_) + tid + 256];
    }
    ws[OFF_RP + g * 512 + tid] = acc0;        // r_h partial
    ws[OFF_RP + g * 512 + 256 + tid] = acc1;  // r_v partial
    return;
  }

  // ---- kw: w = hidden @ W1^T
  __shared__ float h[4][I_];
  __shared__ float red[256];
  const int b0 = blockIdx.x * 4;
#pragma unroll
  for (int k = 0; k < 4; ++k) h[k][tid] = hidden[(size_t)(b0 + k) * I_ + tid];
  __syncthreads();

  const int f = tid;
  const float4* wrow = (const float4*)(W1 + (size_t)f * I_);
  float acc[4] = {0.f, 0.f, 0.f, 0.f};
#pragma unroll 4
  for (int iq = 0; iq < I_ / 4; ++iq) {
    const float4 v = wrow[iq];
    const int i = 4 * iq;
#pragma unroll
    for (int k = 0; k < 4; ++k)
      acc[k] += v.x * h[k][i] + v.y * h[k][i + 1] + v.z * h[k][i + 2] + v.w * h[k][i + 3];
  }
#pragma unroll
  for (int k = 0; k < 4; ++k) ws[OFF_W + (size_t)(b0 + k) * F_ + f] = acc[k];

#pragma unroll
  for (int k = 0; k < 4; ++k) {
    red[tid] = acc[k];
    __syncthreads();
    for (int s = 128; s > 0; s >>= 1) { if (tid < s) red[tid] += red[tid + s]; __syncthreads(); }
    if (tid == 0) ws[OFF_SW + b0 + k] = red[0];
    __syncthreads();
  }
}

// ---------------------------------------------------------------------------
// K1: single pass over inp (1 GB). One block per batch (512 KB contiguous).
//   u[b,t] = inp[b,t,:].w[b,:]   p[b,t] = inp[b,t,:].r_v[:]
// 16 lanes per row (lane slice = 16 floats), 4-step shfl_xor group reduce.
// inp loaded nontemporal (read-once; don't evict L2).
__global__ __launch_bounds__(256) void k1_scan(
    const float* __restrict__ inp, const float* __restrict__ wsw,
    const float* __restrict__ wsrp,
    float* __restrict__ wsu, float* __restrict__ wsp) {
  const int b = blockIdx.x;
  const int tid = threadIdx.x;
  __shared__ float sh[512];  // [0:256) w[b], [256:512) r_v

  float rv = 0.f;
#pragma unroll
  for (int g = 0; g < NG; ++g) rv += wsrp[g * 512 + 256 + tid];
  sh[256 + tid] = rv;
  sh[tid] = wsw[(size_t)b * F_ + tid];
  __syncthreads();

  const int lane = tid & 63;
  const int wid = tid >> 6;   // 0..3
  const int c = lane & 15;    // 16-float slice within row
  const int rg = lane >> 4;   // row within wave's group of 4

  float4 w4[4], rv4[4];
#pragma unroll
  for (int j = 0; j < 4; ++j) {
    w4[j]  = ((const float4*)sh)[c * 4 + j];
    rv4[j] = ((const float4*)(sh + 256))[c * 4 + j];
  }

  const float* base = inp + (size_t)b * S_ * I_;
  float* uo = wsu + (size_t)b * S_;
  float* po = wsp + (size_t)b * S_;

  for (int gg = 0; gg < 32; ++gg) {
    const int row = gg * 16 + wid * 4 + rg;   // block covers 16 contiguous rows/iter
    const v4f* rbase = (const v4f*)(base + (size_t)row * I_ + c * 16);
    float du = 0.f, dp = 0.f;
#pragma unroll
    for (int j = 0; j < 4; ++j) {
      const v4f v = __builtin_nontemporal_load(rbase + j);
      du += v[0] * w4[j].x + v[1] * w4[j].y + v[2] * w4[j].z + v[3] * w4[j].w;
      dp += v[0] * rv4[j].x + v[1] * rv4[j].y + v[2] * rv4[j].z + v[3] * rv4[j].w;
    }
#pragma unroll
    for (int m = 8; m >= 1; m >>= 1) {
      du += __shfl_xor(du, m, 64);
      dp += __shfl_xor(dp, m, 64);
    }
    if (c == 0) { uo[row] = du; po[row] = dp; }
  }
}

// ---------------------------------------------------------------------------
// K2: per-batch epilogue, NO LDS staging — u,p read with wave-uniform addresses
// (scalarizable to s_load: const __restrict, never written in this kernel).
//   s[x] = Wc[x,:].u[b,:] + bc[x]*Sw[b];  q[x] = Wc[x,:].p[b,:]
//   out[b] = sum_x sigmoid(s)[x]*(q[x]+bc[x]*R) + r_h.hidden[b] + const0
__global__ __launch_bounds__(256) void k2_epilogue(
    const float* __restrict__ Wc, const float* __restrict__ bc,
    const float* __restrict__ b2, const float* __restrict__ Wfc,
    const float* __restrict__ bfc, const float* __restrict__ hidden,
    const float* __restrict__ wsu, const float* __restrict__ wsp,
    const float* __restrict__ wsSw, const float* __restrict__ wsrp,
    float* __restrict__ out) {
  const int b0 = blockIdx.x * 4;
  const int x = threadIdx.x;
  const int lane = x & 63;
  const int wid = x >> 6;
  __shared__ float shred[2][4];
  __shared__ float wred[4][4];

  // fold partials: r_h[x], r_v[x]
  float rh = 0.f, rv = 0.f;
#pragma unroll
  for (int g = 0; g < NG; ++g) {
    rh += wsrp[g * 512 + x];
    rv += wsrp[g * 512 + 256 + x];
  }
  // R = sum(r_v); const0 = Wfc.b2 + bfc
  float t0 = rv, t1 = Wfc[x] * b2[x];
#pragma unroll
  for (int m = 32; m >= 1; m >>= 1) {
    t0 += __shfl_xor(t0, m, 64);
    t1 += __shfl_xor(t1, m, 64);
  }
  if (lane == 0) { shred[0][wid] = t0; shred[1][wid] = t1; }
  __syncthreads();
  const float R  = shred[0][0] + shred[0][1] + shred[0][2] + shred[0][3];
  const float c0 = shred[1][0] + shred[1][1] + shred[1][2] + shred[1][3] + bfc[0];

  const float4* wrow = (const float4*)(Wc + (size_t)x * S_);
  float ss[4] = {0.f, 0.f, 0.f, 0.f};
  float qs[4] = {0.f, 0.f, 0.f, 0.f};
  for (int tq = 0; tq < S_ / 4; ++tq) {
    const float4 v = wrow[tq];
    const int t = 4 * tq;
#pragma unroll
    for (int k = 0; k < 4; ++k) {
      const float4 u4 = *(const float4*)(wsu + (size_t)(b0 + k) * S_ + t);  // uniform -> s_load
      const float4 p4 = *(const float4*)(wsp + (size_t)(b0 + k) * S_ + t);
      ss[k] += v.x * u4.x + v.y * u4.y + v.z * u4.z + v.w * u4.w;
      qs[k] += v.x * p4.x + v.y * p4.y + v.z * p4.z + v.w * p4.w;
    }
  }

  const float bcx = bc[x];
#pragma unroll
  for (int k = 0; k < 4; ++k) {
    const float Sw = wsSw[b0 + k];
    const float s = ss[k] + bcx * Sw;
    const float a = 1.f / (1.f + expf(-s));
    float partial = a * (qs[k] + bcx * R) + rh * hidden[(size_t)(b0 + k) * I_ + x];
#pragma unroll
    for (int m = 32; m >= 1; m >>= 1) partial += __shfl_xor(partial, m, 64);
    if (lane == 0) wred[k][wid] = partial;
  }
  __syncthreads();
  if (x < 4)
    out[b0 + x] = wred[x][0] + wred[x][1] + wred[x][2] + wred[x][3] + c0;
}

// ---------------------------------------------------------------------------
extern "C" void kernel_launch(void* const* d_in, const int* in_sizes, int n_in,
                              void* d_out, int out_size, void* d_ws, size_t ws_size,
                              hipStream_t stream) {
  (void)in_sizes; (void)n_in; (void)out_size; (void)ws_size;
  const float* hidden = (const float*)d_in[0];
  const float* inp    = (const float*)d_in[1];
  const float* W1     = (const float*)d_in[2];
  const float* Wc     = (const float*)d_in[3];
  const float* bc     = (const float*)d_in[4];
  const float* W2     = (const float*)d_in[5];
  const float* b2     = (const float*)d_in[6];
  const float* Wfc    = (const float*)d_in[7];
  const float* bfc    = (const float*)d_in[8];
  float* out = (float*)d_out;
  float* ws  = (float*)d_ws;

  hipLaunchKernelGGL(k_pre, dim3(B_ / 4 + NG), dim3(256), 0, stream,
                     hidden, W1, W2, Wfc, ws);
  hipLaunchKernelGGL(k1_scan, dim3(B_), dim3(256), 0, stream,
                     inp, ws + OFF_W, ws + OFF_RP, ws + OFF_U, ws + OFF_P);
  hipLaunchKernelGGL(k2_epilogue, dim3(B_ / 4), dim3(256), 0, stream,
                     Wc, bc, b2, Wfc, bfc, hidden,
                     ws + OFF_U, ws + OFF_P, ws + OFF_SW, ws + OFF_RP, out);
}